// Round 15
// baseline (239.531 us; speedup 1.0000x reference)
//
#include <hip/hip_runtime.h>
#include <hip/hip_fp16.h>
#include <math.h>
#include <stdint.h>

#define BB 32
#define NN 512
#define DDIM 512
#define HH 8
#define DK 64

typedef __attribute__((ext_vector_type(8))) short short8;
typedef __attribute__((ext_vector_type(8))) _Float16 half8;
typedef __attribute__((ext_vector_type(4))) float floatx4;
typedef __attribute__((ext_vector_type(16))) float floatx16;
typedef unsigned short ushort_t;
typedef unsigned int uint_t;

// async global->LDS, 16B/lane; LDS dest = wave-uniform base + lane*16
__device__ __forceinline__ void gl_lds16(const void* g, void* l) {
    __builtin_amdgcn_global_load_lds(
        (const __attribute__((address_space(1))) uint_t*)g,
        (__attribute__((address_space(3))) uint_t*)l,
        16, 0, 0);
}

__device__ __forceinline__ ushort_t f2bf(float f) {  // RNE fp32->bf16
    uint_t u = __builtin_bit_cast(uint_t, f);
    u += 0x7fff + ((u >> 16) & 1);
    return (ushort_t)(u >> 16);
}

__device__ __forceinline__ uint_t pkbf(float a, float b) {
    return (uint_t)f2bf(a) | ((uint_t)f2bf(b) << 16);
}

__device__ __forceinline__ uint_t pkh(float a, float b) {  // 2xf32 -> f16x2 (RTZ, 1 inst)
    return __builtin_bit_cast(uint_t, __builtin_amdgcn_cvt_pkrtz(a, b));
}

__device__ __forceinline__ float h2f(ushort_t u) {
    return __half2float(__ushort_as_half(u));
}

// ---------------------------------------------------------------------------
// merged prep kernel: blockIdx.x partition
// ---------------------------------------------------------------------------
__global__ __launch_bounds__(256) void prep_all(
    const float* __restrict__ x, const float* __restrict__ dist,
    const float* __restrict__ dw,
    const float* __restrict__ Wq, const float* __restrict__ Wk,
    const float* __restrict__ Wv, const float* __restrict__ Wo,
    ushort_t* __restrict__ xb, ushort_t* __restrict__ Tm,
    ushort_t* __restrict__ wqb, ushort_t* __restrict__ wkb,
    ushort_t* __restrict__ wvb, ushort_t* __restrict__ wob) {
    const int bx = blockIdx.x;
    if (bx < 4096) {
        const int i = bx * 256 + threadIdx.x;
        const float4 a = ((const float4*)x)[i * 2 + 0];
        const float4 b = ((const float4*)x)[i * 2 + 1];
        uint4 o;
        o.x = pkbf(a.x, a.y); o.y = pkbf(a.z, a.w);
        o.z = pkbf(b.x, b.y); o.w = pkbf(b.z, b.w);
        *(uint4*)(xb + (size_t)i * 8) = o;
    } else if (bx < 8192) {
        __shared__ float dws[21];
        if (threadIdx.x < 21) dws[threadIdx.x] = (dw[threadIdx.x] - 3.0f) * 1.44269504f;
        __syncthreads();
        const int i = (bx - 4096) * 256 + threadIdx.x;
        float dv[8];
        { const float4 a = ((const float4*)dist)[i * 2 + 0];
          const float4 b = ((const float4*)dist)[i * 2 + 1];
          dv[0]=a.x; dv[1]=a.y; dv[2]=a.z; dv[3]=a.w;
          dv[4]=b.x; dv[5]=b.y; dv[6]=b.z; dv[7]=b.w; }
        ushort_t h[8];
        #pragma unroll
        for (int j = 0; j < 8; ++j) {
            int bin = (int)(dv[j] / 5.0f);
            bin = bin < 0 ? 0 : (bin > 20 ? 20 : bin);
            h[j] = __half_as_ushort(__float2half(dws[bin]));
        }
        uint4 o;
        o.x = (uint_t)h[0] | ((uint_t)h[1] << 16);
        o.y = (uint_t)h[2] | ((uint_t)h[3] << 16);
        o.z = (uint_t)h[4] | ((uint_t)h[5] << 16);
        o.w = (uint_t)h[6] | ((uint_t)h[7] << 16);
        *(uint4*)(Tm + (size_t)i * 8) = o;
    } else {
        const int bw = bx - 8192;            // [0,512)
        const int w = bw >> 7;               // matrix id
        const float* s; ushort_t* d;
        if (w == 0)      { s = Wq; d = wqb; }
        else if (w == 1) { s = Wk; d = wkb; }
        else if (w == 2) { s = Wv; d = wvb; }
        else             { s = Wo; d = wob; }
        const int i = (bw & 127) * 256 + threadIdx.x;
        const float4 a = ((const float4*)s)[i * 2 + 0];
        const float4 b = ((const float4*)s)[i * 2 + 1];
        uint4 o;
        o.x = pkbf(a.x, a.y); o.y = pkbf(a.z, a.w);
        o.z = pkbf(b.x, b.y); o.w = pkbf(b.z, b.w);
        *(uint4*)(d + (size_t)i * 8) = o;
    }
}

// ---------------------------------------------------------------------------
// GEMM core (round-7 proven) — used by gemm_out only.
// NOTE (round-6): no XCD remap on GEMM grids (FETCH 29->100MB, +15us).
// NOTE (rounds 3/8/11): pipelined variants all null on this 4-wave shape.
// ---------------------------------------------------------------------------
#define GEMM_CORE(Aptr, Wptr, M0, N0)                                                   \
    __shared__ ushort_t SH[2][128 * 32];                                                \
    ushort_t* const As = SH[0];                                                         \
    ushort_t* const Bs = SH[1];                                                         \
    const int tid = threadIdx.x;                                                        \
    const int lane = tid & 63, wid = tid >> 6;                                          \
    const int quad = lane >> 4, l15 = lane & 15;                                        \
    const int m0 = (M0), n0 = (N0);                                                     \
    const int wy = wid >> 1, wx = wid & 1;                                              \
    floatx4 acc[4][4];                                                                  \
    _Pragma("unroll") for (int i = 0; i < 4; ++i)                                       \
        _Pragma("unroll") for (int j = 0; j < 4; ++j)                                   \
            _Pragma("unroll") for (int r = 0; r < 4; ++r) acc[i][j][r] = 0.f;           \
    for (int k0 = 0; k0 < DDIM; k0 += 32) {                                             \
        __syncthreads();                                                                \
        _Pragma("unroll") for (int j = 0; j < 4; ++j) {                                 \
            const int t = wid * 4 + j;                                                  \
            const int rowi = ((t & 7) << 4) + (lane >> 2);                              \
            const int cd = (lane & 3) ^ ((rowi >> 1) & 3);                              \
            if (t < 8)                                                                  \
                gl_lds16(Aptr + (size_t)(m0 + rowi) * DDIM + k0 + cd * 8,               \
                         (char*)As + ((t & 7) << 10));                                  \
            else                                                                        \
                gl_lds16(Wptr + (size_t)(n0 + rowi) * DDIM + k0 + cd * 8,               \
                         (char*)Bs + ((t & 7) << 10));                                  \
        }                                                                               \
        __syncthreads();                                                                \
        short8 aw[4], bt[4];                                                            \
        _Pragma("unroll") for (int fi = 0; fi < 4; ++fi) {                              \
            const int r = wy * 64 + fi * 16 + l15;                                      \
            aw[fi] = *(const short8*)((const char*)Bs + r * 64 +                        \
                                      ((quad ^ ((r >> 1) & 3)) << 4));                  \
        }                                                                               \
        _Pragma("unroll") for (int ti = 0; ti < 4; ++ti) {                              \
            const int r = wx * 64 + ti * 16 + l15;                                      \
            bt[ti] = *(const short8*)((const char*)As + r * 64 +                        \
                                      ((quad ^ ((r >> 1) & 3)) << 4));                  \
        }                                                                               \
        _Pragma("unroll") for (int fi = 0; fi < 4; ++fi)                                \
            _Pragma("unroll") for (int ti = 0; ti < 4; ++ti)                            \
                acc[fi][ti] = __builtin_amdgcn_mfma_f32_16x16x32_bf16(                  \
                    aw[fi], bt[ti], acc[fi][ti], 0, 0, 0);                              \
    }

// ---------------------------------------------------------------------------
// Merged QKV projection (round-13 win, -15us): ONE pass computes Q, K, V for
// a 128-token x 128-feature tile; 48 MFMA/wave per K-step, A staged once.
// Round-14: V epilogue emits FRAGMENT-READY VF layout per head slab:
// element (d, kv) at slab + (kv>>4)*1024 + d*16 + (kv&15). attn's PV
// A-operand read (d=lane&31, one 16-kv chunk) is then a fully-coalesced
// wave-wide 2KB global load -> V no longer needs LDS staging in attn.
// Write side here is also fully coalesced (idx -> (qc2,d,half) decode).
// ---------------------------------------------------------------------------
__global__ __launch_bounds__(256)
__attribute__((amdgpu_waves_per_eu(2, 2)))
void gemm_qkv(
    const ushort_t* __restrict__ A,
    const ushort_t* __restrict__ W0, const ushort_t* __restrict__ W1,
    const ushort_t* __restrict__ W2,
    const float* __restrict__ b0, const float* __restrict__ b1,
    const float* __restrict__ b2,
    ushort_t* __restrict__ o0, ushort_t* __restrict__ o1, ushort_t* __restrict__ o2) {
    __shared__ ushort_t SH[4][128 * 32];    // [0]=A tile, [1..3]=Wq/Wk/Wv tiles
    const int tid = threadIdx.x;
    const int lane = tid & 63, wid = tid >> 6;
    const int quad = lane >> 4, l15 = lane & 15;
    const int m0 = blockIdx.x * 128, n0 = blockIdx.y * 128;
    const int wy = wid >> 1, wx = wid & 1;

    floatx4 acc[3][4][4];
    #pragma unroll
    for (int w = 0; w < 3; ++w)
        #pragma unroll
        for (int i = 0; i < 4; ++i)
            #pragma unroll
            for (int j = 0; j < 4; ++j)
                #pragma unroll
                for (int r = 0; r < 4; ++r) acc[w][i][j][r] = 0.f;

    // wave wid stages matrix wid: 0=A (rows m0+), 1..3=W (rows n0+)
    const ushort_t* const stage_src =
        (wid == 0) ? A : (wid == 1 ? W0 : (wid == 2 ? W1 : W2));
    const int stage_base = (wid == 0) ? m0 : n0;

    for (int k0 = 0; k0 < DDIM; k0 += 32) {
        __syncthreads();
        #pragma unroll
        for (int j = 0; j < 8; ++j) {       // 8 x 1KB wave-loads = full 8KB tile
            const int rowi = (j << 4) + (lane >> 2);
            const int cd = (lane & 3) ^ ((rowi >> 1) & 3);
            gl_lds16(stage_src + (size_t)(stage_base + rowi) * DDIM + k0 + cd * 8,
                     (char*)&SH[wid][0] + (j << 10));
        }
        __syncthreads();
        short8 bt[4];
        #pragma unroll
        for (int ti = 0; ti < 4; ++ti) {
            const int r = wx * 64 + ti * 16 + l15;
            bt[ti] = *(const short8*)((const char*)&SH[0][0] + r * 64 +
                                      ((quad ^ ((r >> 1) & 3)) << 4));
        }
        #pragma unroll
        for (int w = 0; w < 3; ++w) {
            short8 aw[4];
            #pragma unroll
            for (int fi = 0; fi < 4; ++fi) {
                const int r = wy * 64 + fi * 16 + l15;
                aw[fi] = *(const short8*)((const char*)&SH[1 + w][0] + r * 64 +
                                          ((quad ^ ((r >> 1) & 3)) << 4));
            }
            #pragma unroll
            for (int fi = 0; fi < 4; ++fi)
                #pragma unroll
                for (int ti = 0; ti < 4; ++ti)
                    acc[w][fi][ti] = __builtin_amdgcn_mfma_f32_16x16x32_bf16(
                        aw[fi], bt[ti], acc[w][fi][ti], 0, 0, 0);
        }
    }

    // ---- Q and K epilogues (direct bf16 [token][512]) ----
    #pragma unroll
    for (int w = 0; w < 2; ++w) {
        const float* const bias = w ? b1 : b0;
        ushort_t* const dst = w ? o1 : o0;
        #pragma unroll
        for (int fi = 0; fi < 4; ++fi) {
            const int f = n0 + wy * 64 + fi * 16 + quad * 4;
            const float4 b4 = *(const float4*)&bias[f];
            #pragma unroll
            for (int ti = 0; ti < 4; ++ti) {
                const int token = m0 + wx * 64 + ti * 16 + l15;
                const float v0 = acc[w][fi][ti][0] + b4.x, v1 = acc[w][fi][ti][1] + b4.y;
                const float v2 = acc[w][fi][ti][2] + b4.z, v3 = acc[w][fi][ti][3] + b4.w;
                uint2 v;
                v.x = pkbf(v0, v1); v.y = pkbf(v2, v3);
                *(uint2*)&dst[(size_t)token * DDIM + f] = v;
            }
        }
    }

    // ---- V epilogue: fp16 VF layout via 16KB LDS transpose (acc[2]) ----
    {
        const int b = m0 >> 9;            // batch (tile within one b)
        const int hh0 = n0 >> 6;          // head of wy==0 half
        const int q0 = m0 & 511;          // token base within b (mult of 128)
        ushort_t* const SHT = &SH[0][0];  // 16KB = [64][128] fp16, chunk-swizzled
        __syncthreads();                  // all K-loop LDS reads complete
        #pragma unroll
        for (int hp = 0; hp < 2; ++hp) {
            if (wy == hp) {
                #pragma unroll
                for (int fi = 0; fi < 4; ++fi) {
                    const int f = n0 + wy * 64 + fi * 16 + quad * 4;
                    const float4 b4 = *(const float4*)&b2[f];
                    #pragma unroll
                    for (int ti = 0; ti < 4; ++ti) {
                        const int q = wx * 64 + ti * 16 + l15;
                        const int qc = q >> 3, qr = q & 7;
                        const float vv[4] = {acc[2][fi][ti][0] + b4.x,
                                             acc[2][fi][ti][1] + b4.y,
                                             acc[2][fi][ti][2] + b4.z,
                                             acc[2][fi][ti][3] + b4.w};
                        #pragma unroll
                        for (int r = 0; r < 4; ++r) {
                            const int d = fi * 16 + quad * 4 + r;
                            SHT[(d * 256 + ((qc ^ (d & 15)) << 4) + qr * 2) >> 1] =
                                __half_as_ushort(__float2half(vv[r]));
                        }
                    }
                }
            }
            __syncthreads();
            const size_t slab = (size_t)(b * HH + hh0 + hp) * DK * NN;
            #pragma unroll
            for (int c = 0; c < 4; ++c) {
                const int idx = c * 256 + tid;          // [0,1024)
                const int d = (idx >> 1) & 63, hf = idx & 1, qc2 = idx >> 7;
                const int qchl = qc2 * 2 + hf;          // SHT chunk (q_local>>3)
                const uint4 vv = *(const uint4*)((const char*)SHT + d * 256 +
                                                 ((qchl ^ (d & 15)) << 4));
                // VF: elem (d, kv=q0+qc2*16+hf*8+j) -> slab + (kv>>4)*1024 + d*16 + (kv&15)
                *(uint4*)&o2[slab + (size_t)((q0 >> 4) + qc2) * 1024 + d * 16 + hf * 8] = vv;
            }
            __syncthreads();
        }
    }
}

// Output projection -> fp32 [token][512]
__global__ __launch_bounds__(256) void gemm_out(
    const ushort_t* __restrict__ A, const ushort_t* __restrict__ Wo,
    const float* __restrict__ bo, float* __restrict__ dst) {
    GEMM_CORE(A, Wo, blockIdx.x * 128, blockIdx.y * 128)
    #pragma unroll
    for (int fi = 0; fi < 4; ++fi) {
        const int f = n0 + wy * 64 + fi * 16 + quad * 4;
        const float4 b4 = *(const float4*)&bo[f];
        #pragma unroll
        for (int ti = 0; ti < 4; ++ti) {
            const int token = m0 + wx * 64 + ti * 16 + l15;
            float4 v;
            v.x = acc[fi][ti][0] + b4.x; v.y = acc[fi][ti][1] + b4.y;
            v.z = acc[fi][ti][2] + b4.z; v.w = acc[fi][ti][3] + b4.w;
            *(float4*)&dst[(size_t)token * DDIM + f] = v;
        }
    }
}

// ---------------------------------------------------------------------------
// Persistent-K MFMA attention, 32x32 MFMA + in-register P.
// Round-14 occupancy doubling: attn was latency-bound at 2 waves/SIMD
// (49us; MfmaUtil 13% ~= MFMA floor, ~23us stall; VGPR only 124 -> LDS and
// grid were the occupancy limits).
//  * V dropped from LDS: read per-fragment from global VF layout (coalesced
//    2KB/wave loads, 64KB/head slab L2-resident; 8 slabs/XCD = 512KB).
//  * Grid 256 -> 512: (h, b, q-half); each block = 8 waves x 32 q rows.
//    Persistent state halves (O 32, bq 16, tv 16 regs).
//  * waves_per_eu(4,4): cap 128 VGPR -> with 64KB LDS, 2 blocks/CU =
//    4 waves/SIMD.
// XCD swizzle kept: chunk 64 -> the 8 heads of one b stay on one XCD
// (T[b] L2-resident; round-7 A/B -4.4us).
// ---------------------------------------------------------------------------
__global__ __launch_bounds__(512)
__attribute__((amdgpu_waves_per_eu(4, 4)))
void attn_fused(
    const ushort_t* __restrict__ Qg, const ushort_t* __restrict__ Kg,
    const ushort_t* __restrict__ Vtg, const ushort_t* __restrict__ Tg,
    ushort_t* __restrict__ aout) {
    __shared__ ushort_t Ks[512 * 64];   // 64KB: row kj, 128B, 8x16B grans, gran g = global g^key(kj)

    const int tid = threadIdx.x, lane = tid & 63, wid = tid >> 6;
    const int l31 = lane & 31, hl = lane >> 5;
    const int p = blockIdx.x;
    const int nid = (p & 7) * 64 + (p >> 3);      // bijective, chunk 64/XCD
    const int h = nid & 7, b = (nid >> 3) & 31, qh = nid >> 8;
    const int qbase = qh * 256 + wid * 32;        // this wave's 32 q rows
    const float K1 = 0.18033688f;                 // 0.125 * log2(e)

    // ---- stage K (once; all 512 kv rows) ----
    #pragma unroll
    for (int j = 0; j < 8; ++j) {
        const int t = wid * 8 + j;
        const int row = t * 8 + (lane >> 3);
        const int key = (row & 7) ^ ((row >> 3) & 7);
        const int g = (lane & 7) ^ key;
        gl_lds16(Kg + (size_t)(b * NN + row) * DDIM + h * DK + g * 8,
                 (char*)Ks + t * 1024);
    }

    // ---- Q fragments (B-operand: n=q=lane&31, k=dk=(lane>>5)*8+j) ----
    short8 bq[4];
    {
        const ushort_t* qp =
            Qg + (size_t)(b * NN + qbase + l31) * DDIM + h * DK + hl * 8;
        #pragma unroll
        for (int st = 0; st < 4; ++st) bq[st] = *(const short8*)(qp + st * 16);
    }

    const ushort_t* const vslab = Vtg + (size_t)(b * HH + h) * DK * NN;

    float lsum = 0.f;
    floatx16 O[2];                       // [dt], C: col=q, row=d
    #pragma unroll
    for (int dt = 0; dt < 2; ++dt)
        #pragma unroll
        for (int r = 0; r < 16; ++r) O[dt][r] = 0.f;

    __syncthreads();   // the only barrier

    for (int kt = 0; kt < 8; ++kt) {
        // T prefetch: tv[kti][g] covers k = kt*64 + kti*32 + g*8 + hl*4 + 0..3
        uint2 tv[2][4];
        {
            const ushort_t* tp =
                Tg + (size_t)(b * NN + qbase + l31) * NN + kt * 64 + hl * 4;
            #pragma unroll
            for (int kti = 0; kti < 2; ++kti)
                #pragma unroll
                for (int g = 0; g < 4; ++g)
                    tv[kti][g] = *(const uint2*)(tp + kti * 32 + g * 8);
        }

        #pragma unroll
        for (int kti = 0; kti < 2; ++kti) {
            // V fragments from global VF layout (coalesced): A-operand,
            // m=d=lane&31(+dt*32), k=(lane>>5)*8+j; chunk = kv/16.
            half8 vf[2][2];   // [dt][ks]
            #pragma unroll
            for (int dt = 0; dt < 2; ++dt) {
                const int d = dt * 32 + l31;
                #pragma unroll
                for (int ks = 0; ks < 2; ++ks)
                    vf[dt][ks] = *(const half8*)&vslab[
                        (size_t)(kt * 4 + kti * 2 + ks) * 1024 + d * 16 + hl * 8];
            }
            // K fragments (A: m=k-row=lane&31(+base), k=dk=(lane>>5)*8+j)
            short8 kf[4];
            {
                const int row = kt * 64 + kti * 32 + l31;
                const int key = (row & 7) ^ ((row >> 3) & 7);
                #pragma unroll
                for (int st = 0; st < 4; ++st)
                    kf[st] = *(const short8*)((const char*)Ks + row * 128 +
                                              (((st * 2 + hl) ^ key) << 4));
            }

            // S^T tile [32k x 32q] = K.Q^T
            floatx16 S;
            #pragma unroll
            for (int r = 0; r < 16; ++r) S[r] = 0.f;
            __builtin_amdgcn_s_setprio(1);
            #pragma unroll
            for (int st = 0; st < 4; ++st)
                S = __builtin_amdgcn_mfma_f32_32x32x16_bf16(
                    kf[st], bq[st], S, 0, 0, 0);
            __builtin_amdgcn_s_setprio(0);

            float ls = 0.f;
            #pragma unroll
            for (int ks = 0; ks < 2; ++ks) {       // 16-k PV step
                float pp[8];
                #pragma unroll
                for (int gg = 0; gg < 2; ++gg) {
                    const uint2 tg = tv[kti][ks * 2 + gg];
                    const float t0 = h2f((ushort_t)tg.x);
                    const float t1 = h2f((ushort_t)(tg.x >> 16));
                    const float t2 = h2f((ushort_t)tg.y);
                    const float t3 = h2f((ushort_t)(tg.y >> 16));
                    const int sb = ks * 8 + gg * 4;
                    pp[gg * 4 + 0] = exp2f(S[sb + 0] * K1 + t0);
                    pp[gg * 4 + 1] = exp2f(S[sb + 1] * K1 + t1);
                    pp[gg * 4 + 2] = exp2f(S[sb + 2] * K1 + t2);
                    pp[gg * 4 + 3] = exp2f(S[sb + 3] * K1 + t3);
                    ls += (pp[gg * 4 + 0] + pp[gg * 4 + 1]) +
                          (pp[gg * 4 + 2] + pp[gg * 4 + 3]);
                }
                // pack own 8 P vals to fp16, half-exchange to B layout:
                // lane's pp[gg*4+r] holds k_off = 8*gg + 4*hl + r.
                // B needs k = 8*hl + j. swap(w0,w2) -> (word0, word2);
                // swap(w1,w3) -> (word1, word3).
                uint_t w0 = pkh(pp[0], pp[1]);   // own pk01
                uint_t w1 = pkh(pp[2], pp[3]);   // own pk23
                uint_t w2 = pkh(pp[4], pp[5]);   // own pk45
                uint_t w3 = pkh(pp[6], pp[7]);   // own pk67
                auto r02 = __builtin_amdgcn_permlane32_swap(w0, w2, false, false);
                auto r13 = __builtin_amdgcn_permlane32_swap(w1, w3, false, false);
                uint4 uu;
                uu.x = r02[0];   // word0 = {w0.lo, w2.lo}
                uu.y = r13[0];   // word1 = {w1.lo, w3.lo}
                uu.z = r02[1];   // word2 = {w0.hi, w2.hi}
                uu.w = r13[1];   // word3 = {w1.hi, w3.hi}
                const half8 bp = __builtin_bit_cast(half8, uu);

                __builtin_amdgcn_s_setprio(1);
                #pragma unroll
                for (int dt = 0; dt < 2; ++dt)
                    O[dt] = __builtin_amdgcn_mfma_f32_32x32x16_f16(
                        vf[dt][ks], bp, O[dt], 0, 0, 0);
                __builtin_amdgcn_s_setprio(0);
            }
            lsum += ls;
        }
    }

    // ---- epilogue: reduce l over lane halves, normalize, write bf16 ----
    {
        float l = lsum;
        l += __shfl_xor(l, 32);
        const float inv = 1.0f / l;
        const size_t orow =
            (size_t)(b * NN + qbase + l31) * DDIM + h * DK;
        #pragma unroll
        for (int dt = 0; dt < 2; ++dt)
            #pragma unroll
            for (int g = 0; g < 4; ++g) {
                const int d = dt * 32 + g * 8 + hl * 4;
                uint2 ov;
                ov.x = pkbf(O[dt][g * 4 + 0] * inv, O[dt][g * 4 + 1] * inv);
                ov.y = pkbf(O[dt][g * 4 + 2] * inv, O[dt][g * 4 + 3] * inv);
                *(uint2*)&aout[orow + d] = ov;
            }
    }
}

extern "C" void kernel_launch(void* const* d_in, const int* in_sizes, int n_in,
                              void* d_out, int out_size, void* d_ws, size_t ws_size,
                              hipStream_t stream) {
    const float* x    = (const float*)d_in[0];
    const float* dist = (const float*)d_in[1];
    const float* Wq   = (const float*)d_in[2];
    const float* bq   = (const float*)d_in[3];
    const float* Wk   = (const float*)d_in[4];
    const float* bk   = (const float*)d_in[5];
    const float* Wv   = (const float*)d_in[6];
    const float* bv   = (const float*)d_in[7];
    const float* Wo   = (const float*)d_in[8];
    const float* bo   = (const float*)d_in[9];
    const float* dw   = (const float*)d_in[10];
    float* out = (float*)d_out;

    const size_t NELT = (size_t)BB * NN * DDIM;   // 8388608
    ushort_t* xb  = (ushort_t*)d_ws;              // x bf16; aliased by ab later
    ushort_t* wqb = xb + NELT;
    ushort_t* wkb = wqb + DDIM * DDIM;
    ushort_t* wvb = wkb + DDIM * DDIM;
    ushort_t* wob = wvb + DDIM * DDIM;
    ushort_t* qb  = wob + DDIM * DDIM;
    ushort_t* kb  = qb + NELT;
    ushort_t* vt  = kb + NELT;                    // fp16, VF tiled layout (from gemm_qkv)
    ushort_t* Tm  = vt + NELT;                    // fp16 bias matrix
    ushort_t* ab  = xb;                           // alias: xb dead after gemm_qkv

    prep_all<<<8704, 256, 0, stream>>>(x, dist, dw, Wq, Wk, Wv, Wo,
                                       xb, Tm, wqb, wkb, wvb, wob);
    gemm_qkv<<<dim3(128, 4), 256, 0, stream>>>(xb, wqb, wkb, wvb, bq, bk, bv,
                                               qb, kb, vt);
    attn_fused<<<512, 512, 0, stream>>>(qb, kb, vt, Tm, ab);
    gemm_out<<<dim3(128, 4), 256, 0, stream>>>(ab, wob, bo, out);
}